// Round 1
// baseline (39442.090 us; speedup 1.0000x reference)
//
#include <hip/hip_runtime.h>
#include <math.h>

// Problem constants (ReservoirLayer: B=8, T=4096, R=1024, F=64, I=32)
#define BB 8
#define TT 4096
#define RR 1024
#define FF 64
#define II 32
#define K96 (FF + II)            // 96 fused input-projection depth
#define GROUPS 8                 // one group per batch element
#define BPG 32                   // blocks per group
#define ROWS_PER_BLOCK (RR / BPG)   // 32
#define THREADS 256
#define JPER 8                   // threads cooperating on one row
#define KV4 (RR / JPER / 4)      // 32 float4 of W_hh per thread (kept in VGPRs)
#define K96PER (K96 / JPER)      // 12 input-proj weights per thread

#define ALPHA 0.9f

// ws layout: [0,1024): group counters (128B spacing). [1024, 1024+64KB): hbuf[2][GROUPS][RR]
#define CNT_BYTES 1024
#define HBUF_FLOATS (2 * GROUPS * RR)

__global__ __launch_bounds__(THREADS, 1)
void reservoir_persistent(const float* __restrict__ feedback,
                          const float* __restrict__ driving,
                          const float* __restrict__ W_fb,
                          const float* __restrict__ W_in,
                          const float* __restrict__ W_hh,
                          const float* __restrict__ bias,
                          float* __restrict__ out,
                          float* __restrict__ hbuf,
                          unsigned int* __restrict__ cnt)
{
    const int tid  = threadIdx.x;
    const int bid  = blockIdx.x;
    const int g    = bid & (GROUPS - 1);   // batch index; XCD-local group (heuristic)
    const int rank = bid >> 3;             // 0..31 within group
    const int lr   = tid >> 3;             // local row 0..31
    const int j    = tid & 7;              // k-slice index within row
    const int row  = rank * ROWS_PER_BLOCK + lr;

    // ---- load W_hh slice into registers: 32 float4 = 128 floats (k in [j*128, j*128+128)) ----
    float4 w4[KV4];
    {
        const float4* whh4 = (const float4*)(W_hh + (size_t)row * RR);
        #pragma unroll
        for (int i = 0; i < KV4; i++) w4[i] = whh4[j * KV4 + i];
    }
    // ---- fused input-projection weights: 12 floats covering k96 in [j*12, j*12+12) ----
    float wfb[K96PER];
    #pragma unroll
    for (int kk = 0; kk < K96PER; kk++) {
        int k = j * K96PER + kk;
        wfb[kk] = (k < FF) ? W_fb[(size_t)row * FF + k]
                           : W_in[(size_t)row * II + (k - FF)];
    }
    const float brow = bias[row];

    __shared__ float ulds[2][128];   // staged [fb(64) | dr(32)] per parity

    const float* fbg = feedback + (size_t)g * TT * FF;
    const float* drg = driving  + (size_t)g * TT * II;

    // stage u for t=0
    if (tid < FF / 4) {
        ((float4*)&ulds[0][0])[tid] = ((const float4*)fbg)[tid];
    } else if (tid < FF / 4 + II / 4) {
        ((float4*)&ulds[0][FF])[tid - FF / 4] = ((const float4*)drg)[tid - FF / 4];
    }

    unsigned int* mycnt = cnt + g * 32;   // 128-byte spaced counters

    __syncthreads();

    for (int t = 0; t < TT; t++) {
        const int pr = (t & 1) ^ 1;  // parity holding h_{t-1}
        const float* hprev = hbuf + ((size_t)pr * GROUPS + g) * RR;
        float*       hcur  = hbuf + ((size_t)(t & 1) * GROUPS + g) * RR;

        const float hold = hprev[row];   // own-row previous state (leak term)

        // ---- recurrent dot: 128 fused FMAs against register-resident W_hh ----
        const float4* hp4 = (const float4*)hprev;
        float4 acc = make_float4(0.f, 0.f, 0.f, 0.f);
        #pragma unroll
        for (int i = 0; i < KV4; i++) {
            float4 hv = hp4[j * KV4 + i];
            acc.x = fmaf(w4[i].x, hv.x, acc.x);
            acc.y = fmaf(w4[i].y, hv.y, acc.y);
            acc.z = fmaf(w4[i].z, hv.z, acc.z);
            acc.w = fmaf(w4[i].w, hv.w, acc.w);
        }
        // ---- fused input projection (K=96 slice of 12) ----
        {
            const float* uv = &ulds[t & 1][j * K96PER];
            #pragma unroll
            for (int kk = 0; kk < K96PER; kk++)
                acc.x = fmaf(wfb[kk], uv[kk], acc.x);
        }

        float s = (acc.x + acc.y) + (acc.z + acc.w);
        s += __shfl_xor(s, 1, 64);
        s += __shfl_xor(s, 2, 64);
        s += __shfl_xor(s, 4, 64);

        if (j == 0) {
            float pre  = s + brow;
            float x    = (1.0f - ALPHA) * hold + ALPHA * pre;
            float hnew = tanhf(x);
            out[((size_t)g * TT + t) * RR + row] = hnew;
            // agent-scope store so it reaches the coherent point for other XCDs
            __hip_atomic_store(&hcur[row], hnew, __ATOMIC_RELAXED, __HIP_MEMORY_SCOPE_AGENT);
        }

        __syncthreads();  // drains vmcnt: all 32 row-stores of this block complete
        if (tid == 0) {
            __hip_atomic_fetch_add(mycnt, 1u, __ATOMIC_RELEASE, __HIP_MEMORY_SCOPE_AGENT);
        }

        // ---- prefetch next step's input vectors while we wait on the barrier ----
        if (t + 1 < TT) {
            const float* fbn = fbg + (size_t)(t + 1) * FF;
            const float* drn = drg + (size_t)(t + 1) * II;
            float* ud = &ulds[(t + 1) & 1][0];
            if (tid < FF / 4) {
                ((float4*)ud)[tid] = ((const float4*)fbn)[tid];
            } else if (tid < FF / 4 + II / 4) {
                ((float4*)(ud + FF))[tid - FF / 4] = ((const float4*)drn)[tid - FF / 4];
            }

            if (tid == 0) {
                const unsigned int target = (unsigned int)(BPG * (t + 1));
                while (__hip_atomic_load(mycnt, __ATOMIC_ACQUIRE, __HIP_MEMORY_SCOPE_AGENT) < target)
                    __builtin_amdgcn_s_sleep(1);
            }
            __syncthreads();  // all threads see fresh h + staged u
        }
    }
}

extern "C" void kernel_launch(void* const* d_in, const int* in_sizes, int n_in,
                              void* d_out, int out_size, void* d_ws, size_t ws_size,
                              hipStream_t stream) {
    const float* feedback = (const float*)d_in[0];
    const float* driving  = (const float*)d_in[1];
    const float* W_fb     = (const float*)d_in[2];
    const float* W_in     = (const float*)d_in[3];
    const float* W_hh     = (const float*)d_in[4];
    const float* bias     = (const float*)d_in[5];
    float* out  = (float*)d_out;

    unsigned int* cnt = (unsigned int*)d_ws;
    float* hbuf = (float*)((char*)d_ws + CNT_BYTES);

    // zero barrier counters + h state (ws is re-poisoned 0xAA before every launch)
    hipMemsetAsync(d_ws, 0, CNT_BYTES + HBUF_FLOATS * sizeof(float), stream);

    void* args[] = { (void*)&feedback, (void*)&driving, (void*)&W_fb, (void*)&W_in,
                     (void*)&W_hh, (void*)&bias, (void*)&out, (void*)&hbuf, (void*)&cnt };
    hipLaunchCooperativeKernel((const void*)reservoir_persistent,
                               dim3(GROUPS * BPG), dim3(THREADS), args, 0, stream);
}

// Round 4
// 11848.058 us; speedup vs baseline: 3.3290x; 3.3290x over previous
//
#include <hip/hip_runtime.h>
#include <math.h>

// ReservoirLayer: B=8, T=4096, R=1024, F=64, I=32
#define TT 4096
#define RR 1024
#define FF 64
#define II 32
#define GROUPS 8                 // one group per batch element
#define BPG 32                   // blocks per group
#define THREADS 256
#define KV4 32                   // float4 of W_hh per thread
#define K96PER 12                // fused input-proj weights per thread
#define ALPHA 0.9f

typedef unsigned long long u64;
typedef unsigned int u32;

#define SLOT_U32 (GROUPS * RR)           // 8192 u32 per parity slot (32 KB)
#define PAD(i) ((i) + (((i) >> 7) << 2)) // +4 floats per 128-float chunk
#define TAGMASK 0x0000000100000001ull

__device__ __forceinline__ u64 ld_rlx64(const u64* p) {
    return __hip_atomic_load(p, __ATOMIC_RELAXED, __HIP_MEMORY_SCOPE_AGENT);
}
__device__ __forceinline__ void st_rlx32(u32* p, u32 v) {
    __hip_atomic_store(p, v, __ATOMIC_RELAXED, __HIP_MEMORY_SCOPE_AGENT);
}

__global__ __launch_bounds__(THREADS, 1)
void reservoir_df(const float* __restrict__ feedback,
                  const float* __restrict__ driving,
                  const float* __restrict__ W_fb,
                  const float* __restrict__ W_in,
                  const float* __restrict__ W_hh,
                  const float* __restrict__ bias,
                  float* __restrict__ out,
                  u32* __restrict__ hbuf)
{
    const int tid  = threadIdx.x;
    const int bid  = blockIdx.x;
    const int g    = bid & 7;              // batch / group
    const int rank = bid >> 3;             // 0..31 within group
    const int lr   = tid >> 3;             // local row 0..31
    const int j    = tid & 7;              // k-slice within row
    const int row  = rank * 32 + lr;

    // W_hh slice: k in [j*128, j*128+128). No asm pinning (round-3 suspect:
    // forced 140-reg pin may have made the launch fail resource validation).
    // If the compiler demotes these to per-step loads they hit L2 (~0.9us/step,
    // tolerated in round 1) — protocol first, W residency next round.
    float4 w4[KV4];
    {
        const float4* whh4 = (const float4*)(W_hh + (size_t)row * RR);
        #pragma unroll
        for (int i = 0; i < KV4; i++) w4[i] = whh4[j * KV4 + i];
    }
    float wfb[K96PER];
    #pragma unroll
    for (int kk = 0; kk < K96PER; kk++) {
        int k = j * K96PER + kk;
        wfb[kk] = (k < FF) ? W_fb[(size_t)row * FF + k]
                           : W_in[(size_t)row * II + (k - FF)];
    }
    const float brow = bias[row];

    __shared__ float hlds[2][1056];   // padded h tile per parity
    __shared__ float ulds[2][128];    // [fb(64) | dr(32)] per parity

    const float* fbg  = feedback + (size_t)g * TT * FF;
    const float* drg  = driving  + (size_t)g * TT * II;
    float*       outg = out + (size_t)g * TT * RR;

    // stage u_0
    if (tid < 16)      *(float4*)&ulds[0][4 * tid] = ((const float4*)fbg)[tid];
    else if (tid < 24) *(float4*)&ulds[0][64 + 4 * (tid - 16)] = ((const float4*)drg)[tid - 16];

    __syncthreads();

    for (int t = 0; t < TT; t++) {
        const int par = t & 1;

        // ---- A: issue next-step u loads into registers (hides under poll) ----
        float4 ureg = make_float4(0.f, 0.f, 0.f, 0.f);
        bool uw = false; int uoff = 0;
        if (t + 1 < TT) {
            if (tid < 16) {
                ureg = ((const float4*)(fbg + (size_t)(t + 1) * FF))[tid];
                uw = true; uoff = 4 * tid;
            } else if (tid < 24) {
                ureg = ((const float4*)(drg + (size_t)(t + 1) * II))[tid - 16];
                uw = true; uoff = 64 + 4 * (tid - 16);
            }
        }

        // ---- B: poll+load h_t: 2 u64 words = 4 tagged fp32 (mantissa-LSB tag).
        // Tag bit for step t is (t>>1)&1; slot t&1's successive occupants are
        // t, t+2, ... so the bit alternates — 1 bit disambiguates fresh/stale.
        const u64* sp = (const u64*)(hbuf + (size_t)par * SLOT_U32 + (size_t)g * RR) + 2 * tid;
        const u64 want = ((u64)((t >> 1) & 1)) * TAGMASK;
        u64 v0 = ld_rlx64(sp), v1 = ld_rlx64(sp + 1);
        while ((v0 & TAGMASK) != want) v0 = ld_rlx64(sp);
        while ((v1 & TAGMASK) != want) v1 = ld_rlx64(sp + 1);
        const float f0 = __uint_as_float((u32)v0);
        const float f1 = __uint_as_float((u32)(v0 >> 32));
        const float f2 = __uint_as_float((u32)v1);
        const float f3 = __uint_as_float((u32)(v1 >> 32));

        // ---- C: coalesced out row t-1 (h_t == out[t-1]); block `rank` owns 32 elems ----
        if (t > 0 && lr == rank) {
            *(float4*)(outg + (size_t)(t - 1) * RR + 4 * tid) = make_float4(f0, f1, f2, f3);
        }

        // ---- D: stage into padded LDS ----
        *(float4*)&hlds[par][PAD(4 * tid)] = make_float4(f0, f1, f2, f3);

        __syncthreads();

        // ---- F: commit next u to LDS (other parity; separated by next sync) ----
        if (uw) *(float4*)&ulds[(t + 1) & 1][uoff] = ureg;

        // ---- G: compute (bank-conflict-free j-sliced float4 reads) ----
        float4 acc = make_float4(0.f, 0.f, 0.f, 0.f);
        const float* hb = &hlds[par][j * 132];
        #pragma unroll
        for (int i = 0; i < KV4; i++) {
            float4 hv = *(const float4*)(hb + 4 * i);
            acc.x = fmaf(w4[i].x, hv.x, acc.x);
            acc.y = fmaf(w4[i].y, hv.y, acc.y);
            acc.z = fmaf(w4[i].z, hv.z, acc.z);
            acc.w = fmaf(w4[i].w, hv.w, acc.w);
        }
        {
            const float* uv = &ulds[par][j * K96PER];
            #pragma unroll
            for (int kk = 0; kk < K96PER; kk++)
                acc.x = fmaf(wfb[kk], uv[kk], acc.x);
        }

        float s = (acc.x + acc.y) + (acc.z + acc.w);
        s += __shfl_xor(s, 1, 64);
        s += __shfl_xor(s, 2, 64);
        s += __shfl_xor(s, 4, 64);

        // ---- H: publish h_{t+1}: one relaxed tagged u32 (tag in mantissa LSB) ----
        if (j == 0) {
            const float hold = hlds[par][PAD(row)];
            const float hnew = tanhf((1.0f - ALPHA) * hold + ALPHA * (s + brow));
            const u32 bits = (__float_as_uint(hnew) & ~1u) | (u32)(((t + 1) >> 1) & 1);
            st_rlx32(hbuf + (size_t)((t + 1) & 1) * SLOT_U32 + (size_t)g * RR + row, bits);
        }
    }

    // ---- final out row TT-1 from h_TT (slot 0, tag bit (4096>>1)&1 == 0) ----
    if (lr == rank) {
        const u64* sp = (const u64*)(hbuf + (size_t)g * RR) + 2 * tid;
        u64 v0 = ld_rlx64(sp), v1 = ld_rlx64(sp + 1);
        while ((v0 & TAGMASK) != 0ull) v0 = ld_rlx64(sp);
        while ((v1 & TAGMASK) != 0ull) v1 = ld_rlx64(sp + 1);
        *(float4*)(outg + (size_t)(TT - 1) * RR + 4 * tid) =
            make_float4(__uint_as_float((u32)v0), __uint_as_float((u32)(v0 >> 32)),
                        __uint_as_float((u32)v1), __uint_as_float((u32)(v1 >> 32)));
    }
}

extern "C" void kernel_launch(void* const* d_in, const int* in_sizes, int n_in,
                              void* d_out, int out_size, void* d_ws, size_t ws_size,
                              hipStream_t stream) {
    const float* feedback = (const float*)d_in[0];
    const float* driving  = (const float*)d_in[1];
    const float* W_fb     = (const float*)d_in[2];
    const float* W_in     = (const float*)d_in[3];
    const float* W_hh     = (const float*)d_in[4];
    const float* bias     = (const float*)d_in[5];
    float* out = (float*)d_out;

    u32* hbuf = (u32*)d_ws;
    // 64 KB total ws (round 1 proved >= 66,560 B available).
    // Slot 0 = 0x00: tag bit 0 + h = 0.0f == h_0, readable immediately at t=0.
    // Slot 1 = 0x01 per byte: tag bit 1 != expected tag 0 at t=1 -> readers
    // spin until the real h_1 stores land.
    hipMemsetAsync(d_ws, 0x00, SLOT_U32 * sizeof(u32), stream);
    hipMemsetAsync((char*)d_ws + SLOT_U32 * sizeof(u32), 0x01, SLOT_U32 * sizeof(u32), stream);

    void* args[] = { (void*)&feedback, (void*)&driving, (void*)&W_fb, (void*)&W_in,
                     (void*)&W_hh, (void*)&bias, (void*)&out, (void*)&hbuf };
    hipError_t ce = hipLaunchCooperativeKernel((const void*)reservoir_df,
                                               dim3(GROUPS * BPG), dim3(THREADS), args, 0, stream);
    if (ce != hipSuccess) {
        // Silent cooperative-launch failure was the prime suspect in rounds 2/3
        // (void return swallows the error -> all-zero output). The kernel uses
        // no grid-wide sync, only intra-group dataflow; at ~120 VGPR / 9.5 KB
        // LDS all 256 blocks co-reside under a plain launch too.
        hipLaunchKernelGGL(reservoir_df, dim3(GROUPS * BPG), dim3(THREADS), 0, stream,
                           feedback, driving, W_fb, W_in, W_hh, bias, out, hbuf);
    }
}